// Round 5
// baseline (880.614 us; speedup 1.0000x reference)
//
#include <hip/hip_runtime.h>
#include <hip/hip_bf16.h>

#define N_NODES 50000
#define N_EDGES 800000
#define N_BUCKETS 64
#define M_PAD 50048

// ---- slice-phased aggregation geometry ------------------------------------
#define NS 8                 // source slices
#define SLICE_DIV 6250       // nodes per slice (50000/8)
#define NC (N_NODES * NS)    // 400000 (slice,dest) cells; cell = s*N + v
#define AGG_BLOCKS 1024      // persistent blocks (4 waves each); exactly resident
#define DPW 13               // dests per wave: 4096*13 = 53248 >= 50000
#define INIT_NB ((NC + 255) / 256)     // 1563
#define SCAN2_NB ((NC + 1023) / 1024)  // 391 (1024 cells per scan block)
#define NXCD 8
#define XBLK (AGG_BLOCKS / NXCD)       // 128 blocks per XCD
#define BAR_STRIDE 128                 // ints per launch (8 xcd x 16 slots)

typedef short short8 __attribute__((ext_vector_type(8)));
typedef float floatx4 __attribute__((ext_vector_type(4)));
typedef float floatx2 __attribute__((ext_vector_type(2)));

// ---- bf16 helpers (RNE) ---------------------------------------------------
__device__ __forceinline__ unsigned short f2bf(float f) {
    unsigned u = __float_as_uint(f);
    unsigned r = (u + 0x7fff + ((u >> 16) & 1)) >> 16;
    return (unsigned short)r;
}
__device__ __forceinline__ float bf2f(unsigned short h) {
    return __uint_as_float(((unsigned)h) << 16);
}
__device__ __forceinline__ void expand2(unsigned u, float& lo, float& hi) {
    lo = __uint_as_float(u << 16);
    hi = __uint_as_float(u & 0xffff0000u);
}

// ---- fp8 e4m3 (OCP) HW conversion helpers ---------------------------------
__device__ __forceinline__ unsigned pack4_fp8(float f0, float f1, float f2, float f3) {
    int v = __builtin_amdgcn_cvt_pk_fp8_f32(f0, f1, 0, false);
    v = __builtin_amdgcn_cvt_pk_fp8_f32(f2, f3, v, true);
    return (unsigned)v;
}
__device__ __forceinline__ void accum_fp8x4(float* a, unsigned u, float w) {
    floatx2 lo = __builtin_amdgcn_cvt_pk_f32_fp8((int)u, false);
    floatx2 hi = __builtin_amdgcn_cvt_pk_f32_fp8((int)u, true);
    a[0] += lo[0] * w; a[1] += lo[1] * w;
    a[2] += hi[0] * w; a[3] += hi[1] * w;
}
__device__ __forceinline__ void accum_fp8x2(float* a, unsigned u, float w) {
    floatx2 lo = __builtin_amdgcn_cvt_pk_f32_fp8((int)u, false);
    a[0] += lo[0] * w; a[1] += lo[1] * w;
}

// async global->LDS, 16B per lane (GEMM staging)
__device__ __forceinline__ void gload16(const void* gp, void* lp) {
    __builtin_amdgcn_global_load_lds(
        (const __attribute__((address_space(1))) unsigned int*)gp,
        (__attribute__((address_space(3))) unsigned int*)lp,
        16, 0, 0);
}

// per-XCD phase barrier: 128 arrivals on a device-scope counter, RMW spin.
// Purely a locality device: timeout degrades to free-running (still correct).
__device__ __forceinline__ void xcd_barrier(int* __restrict__ bar, int slot) {
    __syncthreads();
    if (threadIdx.x == 0) {
        int* p = bar + slot;
        atomicAdd(p, 1);
        int it = 0;
        while (atomicAdd(p, 0) < XBLK && it < 6000) {
            ++it;
            __builtin_amdgcn_s_sleep(4);
        }
    }
    __syncthreads();
}

// ---------------------------------------------------------------------------
// CSR-by-(source-slice, dest) build. cell = s*N_NODES + v.
// cnt2 pre-seeded with the self-loop (1 in the dest's own slice cell).
__global__ void k_init2(int* __restrict__ cnt2, float* __restrict__ gb,
                        int* __restrict__ bar) {
    int i = blockIdx.x * blockDim.x + threadIdx.x;
    if (i < NC) {
        int s = i / N_NODES;
        int v = i - s * N_NODES;
        cnt2[i] = (s == v / SLICE_DIV) ? 1 : 0;   // self-loop pre-count
    }
    if (i < N_BUCKETS * 256) gb[i] = 0.0f;
    if (i < 3 * BAR_STRIDE) bar[i] = 0;
}

__global__ void k_count2(const int* __restrict__ row, const int* __restrict__ col,
                         int* __restrict__ cnt2) {
    int e = blockIdx.x * blockDim.x + threadIdx.x;
    if (e >= N_EDGES) return;
    int s = row[e] / SLICE_DIV;
    atomicAdd(&cnt2[s * N_NODES + col[e]], 1);
}

// dinv from total degree (self already pre-seeded in cnt2)
__global__ void k_dinv(const int* __restrict__ cnt2, float* __restrict__ dinv) {
    int v = blockIdx.x * blockDim.x + threadIdx.x;
    if (v >= N_NODES) return;
    int c = 0;
#pragma unroll
    for (int s = 0; s < NS; ++s) c += cnt2[s * N_NODES + v];
    dinv[v] = 1.0f / sqrtf((float)c);
}

// scan level A: per-1024-cell block sums (256 thr x int4)
__global__ __launch_bounds__(256) void k_scanA2(const int* __restrict__ cnt2,
                                                int* __restrict__ bsum) {
    __shared__ int red[256];
    int t = threadIdx.x;
    int base = blockIdx.x * 1024 + t * 4;
    int sum = 0;
    if (base + 3 < NC) {
        int4 c = *(const int4*)&cnt2[base];
        sum = c.x + c.y + c.z + c.w;
    } else {
#pragma unroll
        for (int k = 0; k < 4; ++k)
            if (base + k < NC) sum += cnt2[base + k];
    }
    red[t] = sum;
    __syncthreads();
    for (int d = 128; d > 0; d >>= 1) {
        if (t < d) red[t] += red[t + d];
        __syncthreads();
    }
    if (t == 0) bsum[blockIdx.x] = red[0];
}

// scan level B: single block over SCAN2_NB (=391) partial sums
__global__ __launch_bounds__(512) void k_scanB2(const int* __restrict__ bsum,
                                                int* __restrict__ bbase) {
    __shared__ int sc[512];
    int t = threadIdx.x;
    int v = (t < SCAN2_NB) ? bsum[t] : 0;
    sc[t] = v;
    __syncthreads();
    for (int d = 1; d < 512; d <<= 1) {
        int x = 0;
        if (t >= d) x = sc[t - d];
        __syncthreads();
        if (t >= d) sc[t] += x;
        __syncthreads();
    }
    if (t < SCAN2_NB) bbase[t] = sc[t] - v;   // exclusive
}

// scan level C: per-cell exclusive offsets (same 1024-cell tiling as A)
__global__ __launch_bounds__(256) void k_scanC2(const int* __restrict__ cnt2,
                                                const int* __restrict__ bbase,
                                                int* __restrict__ off2,
                                                int* __restrict__ cursor2) {
    __shared__ int sc[256];
    int t = threadIdx.x;
    int base = blockIdx.x * 1024 + t * 4;
    int c0 = 0, c1 = 0, c2 = 0, c3 = 0;
    if (base + 3 < NC) {
        int4 c = *(const int4*)&cnt2[base];
        c0 = c.x; c1 = c.y; c2 = c.z; c3 = c.w;
    } else {
        if (base     < NC) c0 = cnt2[base];
        if (base + 1 < NC) c1 = cnt2[base + 1];
        if (base + 2 < NC) c2 = cnt2[base + 2];
        if (base + 3 < NC) c3 = cnt2[base + 3];
    }
    int tsum = c0 + c1 + c2 + c3;
    sc[t] = tsum;
    __syncthreads();
    for (int d = 1; d < 256; d <<= 1) {
        int x = 0;
        if (t >= d) x = sc[t - d];
        __syncthreads();
        if (t >= d) sc[t] += x;
        __syncthreads();
    }
    int tex = sc[t] - tsum + bbase[blockIdx.x];
    int e0 = tex, e1 = tex + c0, e2 = e1 + c1, e3 = e2 + c2;
    if (base     < NC) { off2[base]     = e0; cursor2[base]     = e0; }
    if (base + 1 < NC) { off2[base + 1] = e1; cursor2[base + 1] = e1; }
    if (base + 2 < NC) { off2[base + 2] = e2; cursor2[base + 2] = e2; }
    if (base + 3 == NC - 1) off2[NC] = e3 + c3;   // sentinel (NC % 4 == 0)
    if (base + 3 < NC) { off2[base + 3] = e3; cursor2[base + 3] = e3; }
}

// fill edges + self-loops (fused; order within a cell is irrelevant)
__global__ void k_fill2(const int* __restrict__ row, const int* __restrict__ col,
                        const float* __restrict__ dinv, int* __restrict__ cursor2,
                        int2* __restrict__ epack) {
    int e = blockIdx.x * blockDim.x + threadIdx.x;
    if (e < N_EDGES) {
        int r = row[e];
        int s = r / SLICE_DIV;
        int p = atomicAdd(&cursor2[s * N_NODES + col[e]], 1);
        epack[p] = make_int2(r, __float_as_int(dinv[r]));
    }
    if (e < N_NODES) {
        int s = e / SLICE_DIV;
        int p = atomicAdd(&cursor2[s * N_NODES + e], 1);
        epack[p] = make_int2(e, __float_as_int(dinv[e]));
    }
}

// W [K][N] fp32 -> transposed split bf16 WT{h,l} [N][K] (weights stay exact)
__global__ void k_prepW(const float* __restrict__ W,
                        unsigned short* __restrict__ Th,
                        unsigned short* __restrict__ Tl, int K, int N) {
    int idx = blockIdx.x * blockDim.x + threadIdx.x;
    if (idx >= K * N) return;
    int n = idx / K, k = idx - n * K;
    float v = W[(size_t)k * N + n];
    unsigned short h = f2bf(v);
    Th[idx] = h;
    Tl[idx] = f2bf(v - bf2f(h));
}

// x fp32 -> fp8 e4m3; one thread per 4 features
__global__ void k_prepX8(const float* __restrict__ x, unsigned char* __restrict__ xq) {
    int i = blockIdx.x * blockDim.x + threadIdx.x;
    if (i >= N_NODES * 32) return;
    const float* s = x + (size_t)i * 4;
    *(unsigned*)&xq[(size_t)i * 4] = pack4_fp8(s[0], s[1], s[2], s[3]);
}

// ---------------------------------------------------------------------------
// Slice-phased persistent aggregation: per-XCD prefetch + per-XCD BARRIER.
// Evidence chain: random-gather service pinned at ~1.05 TB/s across all
// structures (r0-r3); r4 showed sequential prefetch streams ON TOP of that
// (FETCH +27MB, 1.32 TB/s) but gathers stayed misses because free-running
// waves decohere across slices. This version phase-locks the 128 blocks of
// each XCD (bid&7, round-robin mapping) with a device-atomic barrier per
// slice: prefetch s+1 is issued before slice-s gathers (overlaps), drained
// by the asm sink, then arrive/wait -> when any peer starts s+1, that slice
// is fully resident in its XCD's L2 (1.6MB x 2 live < 4MB). Barrier has a
// timeout: any residency/mapping pathology degrades to r4 behavior, never
// hangs, never affects correctness. __launch_bounds__(256,4) guarantees all
// 1024 blocks co-resident (4 blocks/CU x 256 CU, 0 LDS, ~50 VGPR).
// POOL=0: bf16 rows out (feeds GEMM). POOL=1: bias+relu+bucketed mean-pool.
template <int DIM, int POOL>
__global__ __launch_bounds__(256, 4) void k_aggp(
    const unsigned char* __restrict__ xq, const int* __restrict__ off2,
    const int2* __restrict__ epack, const float* __restrict__ dinv,
    const float* __restrict__ bias, unsigned short* __restrict__ outb,
    float* __restrict__ gb, int* __restrict__ bar) {
    const int FPL = DIM / 64;   // features per lane per dest: 4 or 2
    const int TABLE_BYTES = N_NODES * DIM;
    const int SLICE_BYTES = SLICE_DIV * DIM;
    const int CA  = (DIM == 256) ? 12512 : 6256;  // align16(ceil(SLICE_BYTES/128))
    const int PFL = (DIM == 256) ? 4 : 2;         // dwordx4 loads per thread
    const int wv = __builtin_amdgcn_readfirstlane(threadIdx.x >> 6);
    const int li = threadIdx.x & 63;
    const int wid = blockIdx.x * 4 + wv;
    const int d0 = wid * DPW;
    const int lblk = blockIdx.x >> 3;             // block index within its XCD
    int* __restrict__ mybar = bar + (blockIdx.x & (NXCD - 1)) * 16;
    const unsigned char* __restrict__ xl = xq + li * FPL;

    float acc[DPW][FPL];
#pragma unroll
    for (int di = 0; di < DPW; ++di)
#pragma unroll
        for (int i = 0; i < FPL; ++i) acc[di][i] = 0.0f;

    // warm slice 0 (blocking), then phase-lock before first gathers
    {
        uint4 pf[4];
        int base = lblk * CA + threadIdx.x * 16;
#pragma unroll
        for (int i = 0; i < PFL; ++i) {
            int q = base + i * 4096;
            q = q > TABLE_BYTES - 16 ? TABLE_BYTES - 16 : q;
            pf[i] = *(const uint4*)(xq + q);
        }
#pragma unroll
        for (int i = 0; i < PFL; ++i)
            asm volatile("" ::"v"(pf[i].x), "v"(pf[i].y), "v"(pf[i].z), "v"(pf[i].w));
    }
    xcd_barrier(mybar, 0);

    for (int s = 0; s < NS; ++s) {   // slice-major sweep (the locality phase)
        int cur[DPW], end[DPW];
        int rounds = 0;
#pragma unroll
        for (int di = 0; di < DPW; ++di) {
            int v = d0 + di;
            int vc = (v < N_NODES) ? v : (N_NODES - 1);
            int cell = s * N_NODES + vc;
            int jb = off2[cell];
            int je = (v < N_NODES) ? off2[cell + 1] : jb;
            cur[di] = jb;
            end[di] = je;
            rounds = max(rounds, je - jb);
        }

        // issue next-slice prefetch; completes under this phase's gathers
        uint4 pf[4];
        const bool have_pf = (s + 1 < NS);
        if (have_pf) {
            int base = (s + 1) * SLICE_BYTES + lblk * CA + threadIdx.x * 16;
#pragma unroll
            for (int i = 0; i < PFL; ++i) {
                int q = base + i * 4096;
                q = q > TABLE_BYTES - 16 ? TABLE_BYTES - 16 : q;
                pf[i] = *(const uint4*)(xq + q);
            }
        }

        for (int r = 0; r < rounds; ++r) {
#pragma unroll
            for (int di = 0; di < DPW; ++di) {
                bool act = cur[di] < end[di];
                int jj = act ? cur[di] : (end[di] - 1);
                jj = jj < 0 ? 0 : jj;
                int2 ed = epack[jj];                    // wave-uniform
                float w = act ? __int_as_float(ed.y) : 0.0f;
                cur[di]++;
                if constexpr (DIM == 256) {
                    unsigned gv = *(const unsigned*)&xl[(size_t)ed.x * DIM];
                    accum_fp8x4(acc[di], gv, w);
                } else {
                    unsigned gv = (unsigned)*(const unsigned short*)&xl[(size_t)ed.x * DIM];
                    accum_fp8x2(acc[di], gv, w);
                }
            }
        }

        // drain prefetch (vmcnt wait lands here), then phase-lock the XCD
        if (have_pf) {
#pragma unroll
            for (int i = 0; i < PFL; ++i)
                asm volatile("" ::"v"(pf[i].x), "v"(pf[i].y), "v"(pf[i].z), "v"(pf[i].w));
            xcd_barrier(mybar, s + 1);
        }
    }

    if constexpr (!POOL) {
#pragma unroll
        for (int di = 0; di < DPW; ++di) {
            int v = d0 + di;
            if (v >= N_NODES) continue;
            float dv = dinv[v];
            if constexpr (DIM == 256) {
                uint2 o;
                o.x = (unsigned)f2bf(acc[di][0] * dv) | ((unsigned)f2bf(acc[di][1] * dv) << 16);
                o.y = (unsigned)f2bf(acc[di][2] * dv) | ((unsigned)f2bf(acc[di][3] * dv) << 16);
                *(uint2*)&outb[(size_t)v * DIM + li * 4] = o;
            } else {
                unsigned o = (unsigned)f2bf(acc[di][0] * dv) | ((unsigned)f2bf(acc[di][1] * dv) << 16);
                *(unsigned*)&outb[(size_t)v * DIM + li * 2] = o;
            }
        }
    } else {
        // DIM == 256 only: relu(acc*dv + b) summed over this wave's dests
        floatx4 bv = *(const floatx4*)&bias[li * 4];
        float ps0 = 0.f, ps1 = 0.f, ps2 = 0.f, ps3 = 0.f;
#pragma unroll
        for (int di = 0; di < DPW; ++di) {
            int v = d0 + di;
            if (v >= N_NODES) continue;
            float dv = dinv[v];
            ps0 += fmaxf(acc[di][0] * dv + bv[0], 0.0f);
            ps1 += fmaxf(acc[di][1] * dv + bv[1], 0.0f);
            ps2 += fmaxf(acc[di][2] * dv + bv[2], 0.0f);
            ps3 += fmaxf(acc[di][3] * dv + bv[3], 0.0f);
        }
        float* g0 = &gb[(wid & (N_BUCKETS - 1)) * 256 + li * 4];
        atomicAdd(g0 + 0, ps0);
        atomicAdd(g0 + 1, ps1);
        atomicAdd(g0 + 2, ps2);
        atomicAdd(g0 + 3, ps3);
    }
}

// ---------------------------------------------------------------------------
// bf16-A x split-bf16-B MFMA GEMM: C = A @ (Bh+Bl) (+bias)(relu)
// B pre-transposed [N][K]. 128x128 tile, BK=32, SINGLE-buffered LDS (32KB ->
// 5 blocks/CU). LDS-staged coalesced epilogue. OUTFP8=1: fp8-e4m3 writeback.
template <int BIAS, int RELU, int OUTFP8>
__global__ __launch_bounds__(256) void k_gemm_b(
    const unsigned short* __restrict__ A,
    const unsigned short* __restrict__ Bh, const unsigned short* __restrict__ Bl,
    const float* __restrict__ bias, void* __restrict__ Cout,
    int M, int K, int N) {
    __shared__ unsigned short smem[4 * 4096];   // 32KB
    unsigned short* As  = smem;                 // 8KB
    unsigned short* BsH = smem + 4096;          // 8KB
    unsigned short* BsL = smem + 8192;          // 8KB
    int tid = threadIdx.x;
    int lane = tid & 63;
    int w = tid >> 6;
    int wr = w & 1, wc = w >> 1;
    int bm = blockIdx.x * 128, bn = blockIdx.y * 128;

    floatx4 acc[4][4];
    floatx4 zero = {0.f, 0.f, 0.f, 0.f};
#pragma unroll
    for (int t = 0; t < 4; ++t)
#pragma unroll
        for (int u = 0; u < 4; ++u) acc[t][u] = zero;

    int c0 = w * 2, c1 = c0 + 1;
    int srow = lane >> 2;
    int kg = ((lane & 3) - ((lane >> 3) & 3)) & 3;
    int kc = kg * 8;
    const unsigned short* Ap0 = A + (size_t)(bm + c0 * 16 + srow) * K + kc;
    const unsigned short* Ap1 = A + (size_t)(bm + c1 * 16 + srow) * K + kc;
    const unsigned short* Bh0 = Bh + (size_t)(bn + c0 * 16 + srow) * K + kc;
    const unsigned short* Bh1 = Bh + (size_t)(bn + c1 * 16 + srow) * K + kc;
    const unsigned short* Bl0 = Bl + (size_t)(bn + c0 * 16 + srow) * K + kc;
    const unsigned short* Bl1 = Bl + (size_t)(bn + c1 * 16 + srow) * K + kc;

    const int KT = K >> 5;
    int fr = lane & 15;
    int fq = lane >> 4;
    int cl = ((fq + (fr >> 1)) & 3) * 8;

    for (int kt = 0; kt < KT; ++kt) {
        int k0 = kt * 32;
        gload16(Ap0 + k0, As + c0 * 512);
        gload16(Ap1 + k0, As + c1 * 512);
        gload16(Bh0 + k0, BsH + c0 * 512);
        gload16(Bh1 + k0, BsH + c1 * 512);
        gload16(Bl0 + k0, BsL + c0 * 512);
        gload16(Bl1 + k0, BsL + c1 * 512);
        __syncthreads();
        short8 av[4], bhv[4], blv[4];
#pragma unroll
        for (int t = 0; t < 4; ++t) {
            av[t]  = *(const short8*)&As[(wr * 64 + t * 16 + fr) * 32 + cl];
            bhv[t] = *(const short8*)&BsH[(wc * 64 + t * 16 + fr) * 32 + cl];
            blv[t] = *(const short8*)&BsL[(wc * 64 + t * 16 + fr) * 32 + cl];
        }
#pragma unroll
        for (int t = 0; t < 4; ++t)
#pragma unroll
            for (int u = 0; u < 4; ++u) {
                acc[t][u] = __builtin_amdgcn_mfma_f32_16x16x32_bf16(av[t], bhv[u], acc[t][u], 0, 0, 0);
                acc[t][u] = __builtin_amdgcn_mfma_f32_16x16x32_bf16(av[t], blv[u], acc[t][u], 0, 0, 0);
            }
        __syncthreads();
    }

    // ---- LDS-staged epilogue (reuses all 32KB) ----
    unsigned short* cq = smem + w * 4096;
#pragma unroll
    for (int u = 0; u < 4; ++u) {
        int colq = u * 16 + fr;
        float bv = BIAS ? bias[bn + wc * 64 + colq] : 0.0f;
#pragma unroll
        for (int t = 0; t < 4; ++t) {
#pragma unroll
            for (int r = 0; r < 4; ++r) {
                float o = acc[t][u][r] + bv;
                if (RELU) o = fmaxf(o, 0.f);
                cq[(t * 16 + fq * 4 + r) * 64 + colq] = f2bf(o);
            }
        }
    }
    __syncthreads();
    int lr = tid >> 4;
    int lc = (tid & 15) * 8;
    int wcq = lc >> 6;
    int lcq = lc & 63;
#pragma unroll
    for (int i = 0; i < 8; ++i) {
        int rowt = i * 16 + lr;
        int wrq = rowt >> 6;
        const unsigned short* src =
            smem + (wrq + wcq * 2) * 4096 + (rowt & 63) * 64 + lcq;
        int rowg = bm + rowt;
        if (rowg < M) {
            if (!OUTFP8) {
                unsigned short* C = (unsigned short*)Cout;
                *(uint4*)&C[(size_t)rowg * N + bn + lc] = *(const uint4*)src;
            } else {
                uint4 b = *(const uint4*)src;
                float f0, f1, f2, f3, f4, f5, f6, f7;
                expand2(b.x, f0, f1); expand2(b.y, f2, f3);
                expand2(b.z, f4, f5); expand2(b.w, f6, f7);
                uint2 q;
                q.x = pack4_fp8(f0, f1, f2, f3);
                q.y = pack4_fp8(f4, f5, f6, f7);
                unsigned char* C8 = (unsigned char*)Cout;
                *(uint2*)&C8[(size_t)rowg * N + bn + lc] = q;
            }
        }
    }
}

// tiny MLP; first reduces the 64 pool buckets
__global__ void k_mlp(const float* __restrict__ gb,
                      const float* __restrict__ Wf1, const float* __restrict__ bf1,
                      const float* __restrict__ Wf2, const float* __restrict__ bf2,
                      const float* __restrict__ Wf3, const float* __restrict__ bf3,
                      float* __restrict__ out) {
    __shared__ float s0[256], s1[128], s2[64];
    int t = threadIdx.x;
    float sum = 0.0f;
    for (int b = 0; b < N_BUCKETS; ++b) sum += gb[b * 256 + t];
    s0[t] = sum * (1.0f / (float)N_NODES);
    __syncthreads();
    if (t < 128) {
        float a = bf1[t];
        for (int k = 0; k < 256; ++k) a += s0[k] * Wf1[k * 128 + t];
        s1[t] = fmaxf(a, 0.0f);
    }
    __syncthreads();
    if (t < 64) {
        float a = bf2[t];
        for (int k = 0; k < 128; ++k) a += s1[k] * Wf2[k * 64 + t];
        s2[t] = fmaxf(a, 0.0f);
    }
    __syncthreads();
    if (t == 0) {
        float a = bf3[0];
        for (int k = 0; k < 64; ++k) a += s2[k] * Wf3[k];
        out[0] = a;
    }
}

extern "C" void kernel_launch(void* const* d_in, const int* in_sizes, int n_in,
                              void* d_out, int out_size, void* d_ws, size_t ws_size,
                              hipStream_t stream) {
    const float* x  = (const float*)d_in[0];
    const int* ei   = (const int*)d_in[1];
    const float* W1 = (const float*)d_in[2];
    const float* b1 = (const float*)d_in[3];
    const float* W2 = (const float*)d_in[4];
    const float* b2 = (const float*)d_in[5];
    const float* W3 = (const float*)d_in[6];
    const float* b3 = (const float*)d_in[7];
    const float* Wf1 = (const float*)d_in[8];
    const float* bf1 = (const float*)d_in[9];
    const float* Wf2 = (const float*)d_in[10];
    const float* bf2 = (const float*)d_in[11];
    const float* Wf3 = (const float*)d_in[12];
    const float* bf3 = (const float*)d_in[13];
    float* out = (float*)d_out;

    char* p = (char*)d_ws;
    auto alloc = [&](size_t bytes) {
        void* r = (void*)p;
        p += (bytes + 255) & ~((size_t)255);
        return r;
    };
    int*   cnt2    = (int*)  alloc((size_t)NC * sizeof(int));
    int*   off2    = (int*)  alloc((size_t)(NC + 1) * sizeof(int));
    int*   cursor2 = (int*)  alloc((size_t)NC * sizeof(int));
    int*   bsum2   = (int*)  alloc(SCAN2_NB * sizeof(int));
    int*   bbase2  = (int*)  alloc(SCAN2_NB * sizeof(int));
    float* dinv    = (float*)alloc(N_NODES * sizeof(float));
    int*   bar     = (int*)  alloc(3 * BAR_STRIDE * sizeof(int));
    int2*  epack   = (int2*) alloc((size_t)(N_EDGES + N_NODES) * sizeof(int2));
    float* gb      = (float*)alloc(N_BUCKETS * 256 * sizeof(float));
    unsigned short* W1h = (unsigned short*)alloc(128 * 256 * 2);
    unsigned short* W1l = (unsigned short*)alloc(128 * 256 * 2);
    unsigned short* W2h = (unsigned short*)alloc(256 * 512 * 2);
    unsigned short* W2l = (unsigned short*)alloc(256 * 512 * 2);
    unsigned short* W3h = (unsigned short*)alloc(512 * 256 * 2);
    unsigned short* W3l = (unsigned short*)alloc(512 * 256 * 2);
    unsigned char*  xq  = (unsigned char*) alloc((size_t)N_NODES * 128);
    unsigned short* t0  = (unsigned short*)alloc((size_t)M_PAD * 128 * 2);
    unsigned char*  h1q = (unsigned char*) alloc((size_t)N_NODES * 256);
    unsigned short* t1  = (unsigned short*)alloc((size_t)M_PAD * 256 * 2);
    unsigned short* h2  = (unsigned short*)alloc((size_t)M_PAD * 512 * 2);
    unsigned char*  t2q = (unsigned char*) alloc((size_t)N_NODES * 256);

    const int* row = ei;
    const int* col = ei + N_EDGES;

    const int NB = (N_NODES + 255) / 256;
    const int EB = (N_EDGES + 255) / 256;

    // CSR-by-(slice,dest) build + norm (7 launches)
    k_init2<<<INIT_NB, 256, 0, stream>>>(cnt2, gb, bar);
    k_count2<<<EB, 256, 0, stream>>>(row, col, cnt2);
    k_dinv<<<NB, 256, 0, stream>>>(cnt2, dinv);
    k_scanA2<<<SCAN2_NB, 256, 0, stream>>>(cnt2, bsum2);
    k_scanB2<<<1, 512, 0, stream>>>(bsum2, bbase2);
    k_scanC2<<<SCAN2_NB, 256, 0, stream>>>(cnt2, bbase2, off2, cursor2);
    k_fill2<<<EB, 256, 0, stream>>>(row, col, dinv, cursor2, epack);

    // weight prep (transpose + exact split) and x -> fp8
    k_prepW<<<(128 * 256 + 255) / 256, 256, 0, stream>>>(W1, W1h, W1l, 128, 256);
    k_prepW<<<(256 * 512 + 255) / 256, 256, 0, stream>>>(W2, W2h, W2l, 256, 512);
    k_prepW<<<(512 * 256 + 255) / 256, 256, 0, stream>>>(W3, W3h, W3l, 512, 256);
    k_prepX8<<<(N_NODES * 32 + 255) / 256, 256, 0, stream>>>(x, xq);

    const int M = N_NODES;
    const int MB = (M + 127) / 128; // 391

    // conv1: t0 = agg(x_fp8) -> bf16; h1 = relu(t0@W1 + b1) -> fp8
    k_aggp<128, 0><<<AGG_BLOCKS, 256, 0, stream>>>(
        xq, off2, epack, dinv, nullptr, t0, nullptr, bar);
    {
        dim3 grid(MB, 256 / 128);
        k_gemm_b<1, 1, 1><<<grid, 256, 0, stream>>>(t0, W1h, W1l, b1, h1q, M, 128, 256);
    }
    // conv2: t1 = agg(h1_fp8) -> bf16; h2 = relu(t1@W2 + b2) -> bf16
    k_aggp<256, 0><<<AGG_BLOCKS, 256, 0, stream>>>(
        h1q, off2, epack, dinv, nullptr, t1, nullptr, bar + BAR_STRIDE);
    {
        dim3 grid(MB, 512 / 128);
        k_gemm_b<1, 1, 0><<<grid, 256, 0, stream>>>(t1, W2h, W2l, b2, h2, M, 256, 512);
    }
    // conv3: t2 = h2@W3 -> fp8; fused agg + bias + relu + bucketed mean-pool
    {
        dim3 grid(MB, 256 / 128);
        k_gemm_b<0, 0, 1><<<grid, 256, 0, stream>>>(h2, W3h, W3l, nullptr, t2q, M, 512, 256);
    }
    k_aggp<256, 1><<<AGG_BLOCKS, 256, 0, stream>>>(
        t2q, off2, epack, dinv, b3, nullptr, gb, bar + 2 * BAR_STRIDE);

    // MLP (reduces buckets internally)
    k_mlp<<<1, 256, 0, stream>>>(gb, Wf1, bf1, Wf2, bf2, Wf3, bf3, out);
}

// Round 7
// 461.938 us; speedup vs baseline: 1.9063x; 1.9063x over previous
//
#include <hip/hip_runtime.h>
#include <hip/hip_bf16.h>

#define N_NODES 50000
#define N_EDGES 800000
#define N_BUCKETS 64
#define M_PAD 50048
#define SCAN_NB 196   // ceil(50000/256)
#define ZROW N_NODES  // index of the all-zero pad row in each feature table

typedef short short8 __attribute__((ext_vector_type(8)));
typedef float floatx4 __attribute__((ext_vector_type(4)));
typedef float floatx2 __attribute__((ext_vector_type(2)));

// ---- bf16 helpers (RNE) ---------------------------------------------------
__device__ __forceinline__ unsigned short f2bf(float f) {
    unsigned u = __float_as_uint(f);
    unsigned r = (u + 0x7fff + ((u >> 16) & 1)) >> 16;
    return (unsigned short)r;
}
__device__ __forceinline__ float bf2f(unsigned short h) {
    return __uint_as_float(((unsigned)h) << 16);
}
__device__ __forceinline__ void expand2(unsigned u, float& lo, float& hi) {
    lo = __uint_as_float(u << 16);
    hi = __uint_as_float(u & 0xffff0000u);
}

// ---- fp8 e4m3 (OCP) HW conversion helpers ---------------------------------
__device__ __forceinline__ unsigned pack4_fp8(float f0, float f1, float f2, float f3) {
    int v = __builtin_amdgcn_cvt_pk_fp8_f32(f0, f1, 0, false);
    v = __builtin_amdgcn_cvt_pk_fp8_f32(f2, f3, v, true);
    return (unsigned)v;
}
// weightless accumulate (rows are pre-scaled by dinv[src] at quantization)
__device__ __forceinline__ void acc4(float* a, unsigned u) {
    floatx2 lo = __builtin_amdgcn_cvt_pk_f32_fp8((int)u, false);
    floatx2 hi = __builtin_amdgcn_cvt_pk_f32_fp8((int)u, true);
    a[0] += lo[0]; a[1] += lo[1];
    a[2] += hi[0]; a[3] += hi[1];
}
__device__ __forceinline__ void acc2(float* a, unsigned u) {
    floatx2 lo = __builtin_amdgcn_cvt_pk_f32_fp8((int)u, false);
    a[0] += lo[0]; a[1] += lo[1];
}

// async global->LDS, 16B per lane (GEMM staging)
__device__ __forceinline__ void gload16(const void* gp, void* lp) {
    __builtin_amdgcn_global_load_lds(
        (const __attribute__((address_space(1))) unsigned int*)gp,
        (__attribute__((address_space(3))) unsigned int*)lp,
        16, 0, 0);
}

// ---------------------------------------------------------------------------
__global__ void k_init(int* __restrict__ cnt, float* __restrict__ gb,
                       unsigned char* __restrict__ xq,
                       unsigned char* __restrict__ h1q,
                       unsigned char* __restrict__ t2q) {
    int i = blockIdx.x * blockDim.x + threadIdx.x;
    if (i < N_NODES) cnt[i] = 0;
    if (i < N_BUCKETS * 256) gb[i] = 0.0f;
    if (blockIdx.x == 0) {   // zero pad-row (gathered by pad edges, adds 0)
        int t = threadIdx.x;
        if (t < 32) ((unsigned*)(xq + (size_t)ZROW * 128))[t] = 0u;
        if (t < 64) ((unsigned*)(h1q + (size_t)ZROW * 256))[t] = 0u;
        if (t < 64) ((unsigned*)(t2q + (size_t)ZROW * 256))[t] = 0u;
    }
}

__global__ void k_count(const int* __restrict__ col, int* __restrict__ cnt) {
    int e = blockIdx.x * blockDim.x + threadIdx.x;
    if (e < N_EDGES) atomicAdd(&cnt[col[e]], 1);
}

// --- 3-phase hierarchical exclusive scan of PADDED capacities --------------
// cap[i] = (cnt[i] + 1 self-loop) rounded up to a multiple of 4 -> every CSR
// segment is int4-aligned with length%4==0; pads reference the zero row.
__global__ __launch_bounds__(256) void k_scanA(const int* __restrict__ cnt,
                                               int* __restrict__ bsum) {
    __shared__ int red[256];
    int t = threadIdx.x;
    int i = blockIdx.x * 256 + t;
    red[t] = (i < N_NODES) ? ((cnt[i] + 4) & ~3) : 0;
    __syncthreads();
    for (int d = 128; d > 0; d >>= 1) {
        if (t < d) red[t] += red[t + d];
        __syncthreads();
    }
    if (t == 0) bsum[blockIdx.x] = red[0];
}

__global__ __launch_bounds__(256) void k_scanB(const int* __restrict__ bsum,
                                               int* __restrict__ bbase,
                                               int* __restrict__ off) {
    __shared__ int sc[256];
    int t = threadIdx.x;
    sc[t] = (t < SCAN_NB) ? bsum[t] : 0;
    __syncthreads();
    for (int d = 1; d < 256; d <<= 1) {
        int v = 0;
        if (t >= d) v = sc[t - d];
        __syncthreads();
        if (t >= d) sc[t] += v;
        __syncthreads();
    }
    if (t < SCAN_NB) bbase[t] = sc[t] - bsum[t];
    if (t == SCAN_NB - 1) off[N_NODES] = sc[t];   // padded total
}

__global__ __launch_bounds__(256) void k_scanC(const int* __restrict__ cnt,
                                               const int* __restrict__ bbase,
                                               int* __restrict__ off,
                                               int* __restrict__ cursor,
                                               float* __restrict__ dinv,
                                               int* __restrict__ esrc) {
    __shared__ int sc[256];
    int t = threadIdx.x;
    int i = blockIdx.x * 256 + t;
    int c = (i < N_NODES) ? cnt[i] : 0;
    int cap = (c + 4) & ~3;
    sc[t] = cap;
    __syncthreads();
    for (int d = 1; d < 256; d <<= 1) {
        int v = 0;
        if (t >= d) v = sc[t - d];
        __syncthreads();
        if (t >= d) sc[t] += v;
        __syncthreads();
    }
    if (i < N_NODES) {
        int excl = sc[t] - cap + bbase[blockIdx.x];
        off[i] = excl;
        cursor[i] = excl;
        dinv[i] = 1.0f / sqrtf((float)(c + 1));
        esrc[excl + c] = i;                          // self-loop
        for (int p = c + 1; p < cap; ++p) esrc[excl + p] = ZROW;  // zero-row pads
    }
}

// fill: src index only (weight is folded into pre-scaled feature rows)
__global__ void k_fill(const int* __restrict__ row, const int* __restrict__ col,
                       int* __restrict__ cursor, int* __restrict__ esrc) {
    int e = blockIdx.x * blockDim.x + threadIdx.x;
    if (e >= N_EDGES) return;
    int p = atomicAdd(&cursor[col[e]], 1);
    esrc[p] = row[e];
}

// W [K][N] fp32 -> transposed split bf16 WT{h,l} [N][K]. EXACT weights:
// r6 post-mortem showed single-bf16 weights add a SYSTEMATIC error shared by
// all 50K nodes (no mean-pool cancellation) -> absmax 4.8e-6 > 3.3e-6 thresh.
__global__ void k_prepW(const float* __restrict__ W,
                        unsigned short* __restrict__ Th,
                        unsigned short* __restrict__ Tl, int K, int N) {
    int idx = blockIdx.x * blockDim.x + threadIdx.x;
    if (idx >= K * N) return;
    int n = idx / K, k = idx - n * K;
    float v = W[(size_t)k * N + n];
    unsigned short h = f2bf(v);
    Th[idx] = h;
    Tl[idx] = f2bf(v - bf2f(h));
}

// x fp32 -> fp8 e4m3, pre-scaled by dinv[node]; one thread per 4 features
__global__ void k_prepX8(const float* __restrict__ x, const float* __restrict__ dinv,
                         unsigned char* __restrict__ xq) {
    int i = blockIdx.x * blockDim.x + threadIdx.x;
    if (i >= N_NODES * 32) return;
    float sc = dinv[i >> 5];
    const float* s = x + (size_t)i * 4;
    *(unsigned*)&xq[(size_t)i * 4] = pack4_fp8(s[0] * sc, s[1] * sc, s[2] * sc, s[3] * sc);
}

// ---------------------------------------------------------------------------
// Wave-per-node weightless aggregation over pre-scaled fp8 rows, fp32 accum.
// r0-r5 synthesis: gather service is pinned at ~1.05 TB/s of scattered L2-miss
// traffic regardless of structure/concurrency/DIM -- so use the cheapest
// proven structure (r0) with halved descriptor traffic (bare int src; weight
// folded into the row data; pads hit the zero row).
// POOL=0: bf16 row out (*dinv[v], feeds GEMM). POOL=1: bias+relu+bucket-pool.
template <int DIM, int POOL>
__global__ __launch_bounds__(256) void k_agg(
    const unsigned char* __restrict__ xq, const int* __restrict__ off,
    const int* __restrict__ esrc, const float* __restrict__ dinv,
    const float* __restrict__ bias, unsigned short* __restrict__ outb,
    float* __restrict__ gb) {
    const int FPL = DIM / 64;     // fp8 bytes per lane: 4 (256) or 2 (128)
    __shared__ float gpart[256];
    if constexpr (POOL) {
        gpart[threadIdx.x] = 0.0f;
        __syncthreads();
    }
    int wv = threadIdx.x >> 6;
    int li = threadIdx.x & 63;
    int v = blockIdx.x * 4 + wv;      // grid divides N exactly
    int f = li * FPL;
    const unsigned char* __restrict__ xf = xq + f;
    float a0[FPL], a1[FPL], a2[FPL], a3[FPL];
#pragma unroll
    for (int i = 0; i < FPL; ++i) { a0[i] = 0.f; a1[i] = 0.f; a2[i] = 0.f; a3[i] = 0.f; }
    int j = off[v], e = off[v + 1];   // int4-aligned, length % 4 == 0
    for (; j + 8 <= e; j += 8) {
        int4 dA = *(const int4*)&esrc[j];
        int4 dB = *(const int4*)&esrc[j + 4];
        if constexpr (DIM == 256) {
            unsigned g0 = *(const unsigned*)&xf[(size_t)dA.x * DIM];
            unsigned g1 = *(const unsigned*)&xf[(size_t)dA.y * DIM];
            unsigned g2 = *(const unsigned*)&xf[(size_t)dA.z * DIM];
            unsigned g3 = *(const unsigned*)&xf[(size_t)dA.w * DIM];
            unsigned g4 = *(const unsigned*)&xf[(size_t)dB.x * DIM];
            unsigned g5 = *(const unsigned*)&xf[(size_t)dB.y * DIM];
            unsigned g6 = *(const unsigned*)&xf[(size_t)dB.z * DIM];
            unsigned g7 = *(const unsigned*)&xf[(size_t)dB.w * DIM];
            acc4(a0, g0); acc4(a1, g1); acc4(a2, g2); acc4(a3, g3);
            acc4(a0, g4); acc4(a1, g5); acc4(a2, g6); acc4(a3, g7);
        } else {
            unsigned g0 = *(const unsigned short*)&xf[(size_t)dA.x * DIM];
            unsigned g1 = *(const unsigned short*)&xf[(size_t)dA.y * DIM];
            unsigned g2 = *(const unsigned short*)&xf[(size_t)dA.z * DIM];
            unsigned g3 = *(const unsigned short*)&xf[(size_t)dA.w * DIM];
            unsigned g4 = *(const unsigned short*)&xf[(size_t)dB.x * DIM];
            unsigned g5 = *(const unsigned short*)&xf[(size_t)dB.y * DIM];
            unsigned g6 = *(const unsigned short*)&xf[(size_t)dB.z * DIM];
            unsigned g7 = *(const unsigned short*)&xf[(size_t)dB.w * DIM];
            acc2(a0, g0); acc2(a1, g1); acc2(a2, g2); acc2(a3, g3);
            acc2(a0, g4); acc2(a1, g5); acc2(a2, g6); acc2(a3, g7);
        }
    }
    if (j < e) {  // exactly 4 left
        int4 dA = *(const int4*)&esrc[j];
        if constexpr (DIM == 256) {
            acc4(a0, *(const unsigned*)&xf[(size_t)dA.x * DIM]);
            acc4(a1, *(const unsigned*)&xf[(size_t)dA.y * DIM]);
            acc4(a2, *(const unsigned*)&xf[(size_t)dA.z * DIM]);
            acc4(a3, *(const unsigned*)&xf[(size_t)dA.w * DIM]);
        } else {
            acc2(a0, *(const unsigned short*)&xf[(size_t)dA.x * DIM]);
            acc2(a1, *(const unsigned short*)&xf[(size_t)dA.y * DIM]);
            acc2(a2, *(const unsigned short*)&xf[(size_t)dA.z * DIM]);
            acc2(a3, *(const unsigned short*)&xf[(size_t)dA.w * DIM]);
        }
    }
    float dv = dinv[v];
    float acc[FPL];
#pragma unroll
    for (int i = 0; i < FPL; ++i)
        acc[i] = ((a0[i] + a1[i]) + (a2[i] + a3[i])) * dv;
    if constexpr (!POOL) {
        if constexpr (DIM == 256) {
            uint2 o;
            o.x = (unsigned)f2bf(acc[0]) | ((unsigned)f2bf(acc[1]) << 16);
            o.y = (unsigned)f2bf(acc[2]) | ((unsigned)f2bf(acc[3]) << 16);
            *(uint2*)&outb[(size_t)v * DIM + f] = o;
        } else {
            unsigned o = (unsigned)f2bf(acc[0]) | ((unsigned)f2bf(acc[1]) << 16);
            *(unsigned*)&outb[(size_t)v * DIM + f] = o;
        }
    } else {
#pragma unroll
        for (int i = 0; i < FPL; ++i) {
            float r = fmaxf(acc[i] + bias[f + i], 0.0f);
            atomicAdd(&gpart[f + i], r);
        }
        __syncthreads();
        atomicAdd(&gb[(blockIdx.x & (N_BUCKETS - 1)) * 256 + threadIdx.x],
                  gpart[threadIdx.x]);
    }
}

// ---------------------------------------------------------------------------
// bf16-A x split-bf16-B MFMA GEMM: C = A @ (Bh+Bl) (+bias)(relu)(*dinv)
// B pre-transposed [N][K]. 128x128 tile, BK=32, single-buffered LDS staging
// (24KB) with full-32KB LDS-staged coalesced epilogue. OUTFP8: fp8 writeback;
// DVSCALE: multiply row rowg by dinv[rowg] (folds the agg edge weight).
template <int BIAS, int RELU, int OUTFP8, int DVSCALE>
__global__ __launch_bounds__(256) void k_gemm_b(
    const unsigned short* __restrict__ A,
    const unsigned short* __restrict__ Bh, const unsigned short* __restrict__ Bl,
    const float* __restrict__ bias, const float* __restrict__ dinv,
    void* __restrict__ Cout, int M, int K, int N) {
    __shared__ unsigned short smem[4 * 4096];   // 32KB (epilogue uses all)
    unsigned short* As  = smem;                 // 8KB
    unsigned short* BsH = smem + 4096;          // 8KB
    unsigned short* BsL = smem + 8192;          // 8KB
    int tid = threadIdx.x;
    int lane = tid & 63;
    int w = tid >> 6;
    int wr = w & 1, wc = w >> 1;
    int bm = blockIdx.x * 128, bn = blockIdx.y * 128;

    floatx4 acc[4][4];
    floatx4 zero = {0.f, 0.f, 0.f, 0.f};
#pragma unroll
    for (int t = 0; t < 4; ++t)
#pragma unroll
        for (int u = 0; u < 4; ++u) acc[t][u] = zero;

    int c0 = w * 2, c1 = c0 + 1;
    int srow = lane >> 2;
    int kg = ((lane & 3) - ((lane >> 3) & 3)) & 3;
    int kc = kg * 8;
    const unsigned short* Ap0 = A + (size_t)(bm + c0 * 16 + srow) * K + kc;
    const unsigned short* Ap1 = A + (size_t)(bm + c1 * 16 + srow) * K + kc;
    const unsigned short* Bh0 = Bh + (size_t)(bn + c0 * 16 + srow) * K + kc;
    const unsigned short* Bh1 = Bh + (size_t)(bn + c1 * 16 + srow) * K + kc;
    const unsigned short* Bl0 = Bl + (size_t)(bn + c0 * 16 + srow) * K + kc;
    const unsigned short* Bl1 = Bl + (size_t)(bn + c1 * 16 + srow) * K + kc;

    const int KT = K >> 5;
    int fr = lane & 15;
    int fq = lane >> 4;
    int cl = ((fq + (fr >> 1)) & 3) * 8;

    for (int kt = 0; kt < KT; ++kt) {
        int k0 = kt * 32;
        gload16(Ap0 + k0, As + c0 * 512);
        gload16(Ap1 + k0, As + c1 * 512);
        gload16(Bh0 + k0, BsH + c0 * 512);
        gload16(Bh1 + k0, BsH + c1 * 512);
        gload16(Bl0 + k0, BsL + c0 * 512);
        gload16(Bl1 + k0, BsL + c1 * 512);
        __syncthreads();
        short8 av[4], bhv[4], blv[4];
#pragma unroll
        for (int t = 0; t < 4; ++t) {
            av[t]  = *(const short8*)&As[(wr * 64 + t * 16 + fr) * 32 + cl];
            bhv[t] = *(const short8*)&BsH[(wc * 64 + t * 16 + fr) * 32 + cl];
            blv[t] = *(const short8*)&BsL[(wc * 64 + t * 16 + fr) * 32 + cl];
        }
#pragma unroll
        for (int t = 0; t < 4; ++t)
#pragma unroll
            for (int u = 0; u < 4; ++u) {
                acc[t][u] = __builtin_amdgcn_mfma_f32_16x16x32_bf16(av[t], bhv[u], acc[t][u], 0, 0, 0);
                acc[t][u] = __builtin_amdgcn_mfma_f32_16x16x32_bf16(av[t], blv[u], acc[t][u], 0, 0, 0);
            }
        __syncthreads();
    }

    // ---- LDS-staged epilogue (reuses all 32KB) ----
    unsigned short* cq = smem + w * 4096;
#pragma unroll
    for (int u = 0; u < 4; ++u) {
        int colq = u * 16 + fr;
        float bv = BIAS ? bias[bn + wc * 64 + colq] : 0.0f;
#pragma unroll
        for (int t = 0; t < 4; ++t) {
#pragma unroll
            for (int r = 0; r < 4; ++r) {
                float o = acc[t][u][r] + bv;
                if (RELU) o = fmaxf(o, 0.f);
                cq[(t * 16 + fq * 4 + r) * 64 + colq] = f2bf(o);
            }
        }
    }
    __syncthreads();
    int lr = tid >> 4;
    int lc = (tid & 15) * 8;
    int wcq = lc >> 6;
    int lcq = lc & 63;
#pragma unroll
    for (int i = 0; i < 8; ++i) {
        int rowt = i * 16 + lr;
        int wrq = rowt >> 6;
        const unsigned short* src =
            smem + (wrq + wcq * 2) * 4096 + (rowt & 63) * 64 + lcq;
        int rowg = bm + rowt;
        if (rowg < M) {
            if (!OUTFP8) {
                unsigned short* C = (unsigned short*)Cout;
                *(uint4*)&C[(size_t)rowg * N + bn + lc] = *(const uint4*)src;
            } else {
                float sc = DVSCALE ? dinv[rowg] : 1.0f;
                uint4 b = *(const uint4*)src;
                float f0, f1, f2, f3, f4, f5, f6, f7;
                expand2(b.x, f0, f1); expand2(b.y, f2, f3);
                expand2(b.z, f4, f5); expand2(b.w, f6, f7);
                uint2 q;
                q.x = pack4_fp8(f0 * sc, f1 * sc, f2 * sc, f3 * sc);
                q.y = pack4_fp8(f4 * sc, f5 * sc, f6 * sc, f7 * sc);
                unsigned char* C8 = (unsigned char*)Cout;
                *(uint2*)&C8[(size_t)rowg * N + bn + lc] = q;
            }
        }
    }
}

// tiny MLP; first reduces the 64 pool buckets
__global__ void k_mlp(const float* __restrict__ gb,
                      const float* __restrict__ Wf1, const float* __restrict__ bf1,
                      const float* __restrict__ Wf2, const float* __restrict__ bf2,
                      const float* __restrict__ Wf3, const float* __restrict__ bf3,
                      float* __restrict__ out) {
    __shared__ float s0[256], s1[128], s2[64];
    int t = threadIdx.x;
    float sum = 0.0f;
    for (int b = 0; b < N_BUCKETS; ++b) sum += gb[b * 256 + t];
    s0[t] = sum * (1.0f / (float)N_NODES);
    __syncthreads();
    if (t < 128) {
        float a = bf1[t];
        for (int k = 0; k < 256; ++k) a += s0[k] * Wf1[k * 128 + t];
        s1[t] = fmaxf(a, 0.0f);
    }
    __syncthreads();
    if (t < 64) {
        float a = bf2[t];
        for (int k = 0; k < 128; ++k) a += s1[k] * Wf2[k * 64 + t];
        s2[t] = fmaxf(a, 0.0f);
    }
    __syncthreads();
    if (t == 0) {
        float a = bf3[0];
        for (int k = 0; k < 64; ++k) a += s2[k] * Wf3[k];
        out[0] = a;
    }
}

extern "C" void kernel_launch(void* const* d_in, const int* in_sizes, int n_in,
                              void* d_out, int out_size, void* d_ws, size_t ws_size,
                              hipStream_t stream) {
    const float* x  = (const float*)d_in[0];
    const int* ei   = (const int*)d_in[1];
    const float* W1 = (const float*)d_in[2];
    const float* b1 = (const float*)d_in[3];
    const float* W2 = (const float*)d_in[4];
    const float* b2 = (const float*)d_in[5];
    const float* W3 = (const float*)d_in[6];
    const float* b3 = (const float*)d_in[7];
    const float* Wf1 = (const float*)d_in[8];
    const float* bf1 = (const float*)d_in[9];
    const float* Wf2 = (const float*)d_in[10];
    const float* bf2 = (const float*)d_in[11];
    const float* Wf3 = (const float*)d_in[12];
    const float* bf3 = (const float*)d_in[13];
    float* out = (float*)d_out;

    char* p = (char*)d_ws;
    auto alloc = [&](size_t bytes) {
        void* r = (void*)p;
        p += (bytes + 255) & ~((size_t)255);
        return r;
    };
    int*   cnt    = (int*)  alloc(N_NODES * sizeof(int));
    int*   off    = (int*)  alloc((N_NODES + 1) * sizeof(int));
    int*   cursor = (int*)  alloc(N_NODES * sizeof(int));
    int*   bsum   = (int*)  alloc(SCAN_NB * sizeof(int));
    int*   bbase  = (int*)  alloc(SCAN_NB * sizeof(int));
    float* dinv   = (float*)alloc(N_NODES * sizeof(float));
    int*   esrc   = (int*)  alloc((size_t)(N_EDGES + 4 * N_NODES) * sizeof(int));
    float* gb     = (float*)alloc(N_BUCKETS * 256 * sizeof(float));
    unsigned short* W1h = (unsigned short*)alloc(128 * 256 * 2);
    unsigned short* W1l = (unsigned short*)alloc(128 * 256 * 2);
    unsigned short* W2h = (unsigned short*)alloc(256 * 512 * 2);
    unsigned short* W2l = (unsigned short*)alloc(256 * 512 * 2);
    unsigned short* W3h = (unsigned short*)alloc(512 * 256 * 2);
    unsigned short* W3l = (unsigned short*)alloc(512 * 256 * 2);
    unsigned char*  xq  = (unsigned char*) alloc((size_t)(N_NODES + 1) * 128);
    unsigned short* t0  = (unsigned short*)alloc((size_t)M_PAD * 128 * 2);
    unsigned char*  h1q = (unsigned char*) alloc((size_t)(N_NODES + 1) * 256);
    unsigned short* t1  = (unsigned short*)alloc((size_t)M_PAD * 256 * 2);
    unsigned short* h2  = (unsigned short*)alloc((size_t)M_PAD * 512 * 2);
    unsigned char*  t2q = (unsigned char*) alloc((size_t)(N_NODES + 1) * 256);

    const int* row = ei;
    const int* col = ei + N_EDGES;

    const int NB = (N_NODES + 255) / 256;
    const int EB = (N_EDGES + 255) / 256;

    // CSR build + norm (scan over 4-padded capacities incl. self-loop)
    k_init<<<NB, 256, 0, stream>>>(cnt, gb, xq, h1q, t2q);
    k_count<<<EB, 256, 0, stream>>>(col, cnt);
    k_scanA<<<SCAN_NB, 256, 0, stream>>>(cnt, bsum);
    k_scanB<<<1, 256, 0, stream>>>(bsum, bbase, off);
    k_scanC<<<SCAN_NB, 256, 0, stream>>>(cnt, bbase, off, cursor, dinv, esrc);
    k_fill<<<EB, 256, 0, stream>>>(row, col, cursor, esrc);

    // weight prep (transpose + exact split) and x -> pre-scaled fp8
    k_prepW<<<(128 * 256 + 255) / 256, 256, 0, stream>>>(W1, W1h, W1l, 128, 256);
    k_prepW<<<(256 * 512 + 255) / 256, 256, 0, stream>>>(W2, W2h, W2l, 256, 512);
    k_prepW<<<(512 * 256 + 255) / 256, 256, 0, stream>>>(W3, W3h, W3l, 512, 256);
    k_prepX8<<<(N_NODES * 32 + 255) / 256, 256, 0, stream>>>(x, dinv, xq);

    const int M = N_NODES;
    const int MB = (M + 127) / 128; // 391

    // conv1: t0 = agg(xq)*dinv -> bf16; h1q = relu(t0@W1+b1)*dinv -> fp8
    k_agg<128, 0><<<N_NODES / 4, 256, 0, stream>>>(
        xq, off, esrc, dinv, nullptr, t0, nullptr);
    {
        dim3 grid(MB, 256 / 128);
        k_gemm_b<1, 1, 1, 1><<<grid, 256, 0, stream>>>(t0, W1h, W1l, b1, dinv, h1q, M, 128, 256);
    }
    // conv2: t1 = agg(h1q)*dinv -> bf16; h2 = relu(t1@W2+b2) -> bf16
    k_agg<256, 0><<<N_NODES / 4, 256, 0, stream>>>(
        h1q, off, esrc, dinv, nullptr, t1, nullptr);
    {
        dim3 grid(MB, 512 / 128);
        k_gemm_b<1, 1, 0, 0><<<grid, 256, 0, stream>>>(t1, W2h, W2l, b2, nullptr, h2, M, 256, 512);
    }
    // conv3: t2q = (h2@W3)*dinv -> fp8; fused agg + bias + relu + mean-pool
    {
        dim3 grid(MB, 256 / 128);
        k_gemm_b<0, 0, 1, 1><<<grid, 256, 0, stream>>>(h2, W3h, W3l, nullptr, dinv, t2q, M, 512, 256);
    }
    k_agg<256, 1><<<N_NODES / 4, 256, 0, stream>>>(
        t2q, off, esrc, dinv, b3, nullptr, gb);

    // MLP (reduces buckets internally)
    k_mlp<<<1, 256, 0, stream>>>(gb, Wf1, bf1, Wf2, bf2, Wf3, bf3, out);
}